// Round 5
// baseline (148.541 us; speedup 1.0000x reference)
//
#include <hip/hip_runtime.h>
#include <math.h>

// loss = -sum_ij d1[i,j] * log(d2[i,j] + 1e-5), fp32 in, scalar fp32 out.
// Roofline: 134 MB read -> ~21 us @ 6.3 TB/s.
// R1/R2: lane-contiguous but 2-4 loads in flight -> 2.4 TB/s (latency-bound).
// R3/R4: 8-deep in flight but lane-stride-64B (64 lines per wave-instr)
//        -> both exactly 3.07 TB/s = 5.0 B/cyc/CU; in-flight depth no longer
//        the variable. Theory: per-instruction cache-line count limits the
//        L1 request path. This round: lane-contiguous layout (16 lines/instr,
//        4 lanes/line) AND asm-pinned 8-deep in-flight with partial vmcnt.

#define EPS 1e-5f
#define BLOCK 256

typedef float v4f __attribute__((ext_vector_type(4)));

__global__ __launch_bounds__(BLOCK) void cep_loss_kernel(
        const float* __restrict__ d1,
        const float* __restrict__ d2,
        float* __restrict__ partials) {
    // Per input, block covers 4 chunks x 4KB; thread t reads float4 at
    // chunk_base + t*16B (lane-contiguous within each wave instruction).
    size_t blockBase = (size_t)blockIdx.x * 4096;  // floats per input per block
    // Base pointers at chunk1/chunk3; chunk0/chunk2 reached via offset:-4096.
    const char* q1a = (const char*)(d1 + blockBase) + (size_t)threadIdx.x * 16 + 4096;
    const char* q1b = q1a + 8192;
    const char* q2a = (const char*)(d2 + blockBase) + (size_t)threadIdx.x * 16 + 4096;
    const char* q2b = q2a + 8192;

    v4f a0, b0, a1, b1, a2, b2, a3, b3;
    // 8 coalesced loads back-to-back: 8 KB/wave in flight, no waits between.
    asm volatile(
        "global_load_dwordx4 %0, %8, off offset:-4096\n\t"   // a: chunk0
        "global_load_dwordx4 %1, %10, off offset:-4096\n\t"  // b: chunk0
        "global_load_dwordx4 %2, %8, off\n\t"                // a: chunk1
        "global_load_dwordx4 %3, %10, off\n\t"               // b: chunk1
        "global_load_dwordx4 %4, %9, off offset:-4096\n\t"   // a: chunk2
        "global_load_dwordx4 %5, %11, off offset:-4096\n\t"  // b: chunk2
        "global_load_dwordx4 %6, %9, off\n\t"                // a: chunk3
        "global_load_dwordx4 %7, %11, off\n\t"               // b: chunk3
        : "=v"(a0), "=v"(b0), "=v"(a1), "=v"(b1),
          "=v"(a2), "=v"(b2), "=v"(a3), "=v"(b3)
        : "v"(q1a), "v"(q1b), "v"(q2a), "v"(q2b)
        : "memory");

    float acc0, acc1, acc2, acc3;

    asm volatile("s_waitcnt vmcnt(6)" : "+v"(a0), "+v"(b0));
    acc0 = a0.x * __logf(b0.x + EPS);
    acc1 = a0.y * __logf(b0.y + EPS);
    acc2 = a0.z * __logf(b0.z + EPS);
    acc3 = a0.w * __logf(b0.w + EPS);

    asm volatile("s_waitcnt vmcnt(4)" : "+v"(a1), "+v"(b1));
    acc0 += a1.x * __logf(b1.x + EPS);
    acc1 += a1.y * __logf(b1.y + EPS);
    acc2 += a1.z * __logf(b1.z + EPS);
    acc3 += a1.w * __logf(b1.w + EPS);

    asm volatile("s_waitcnt vmcnt(2)" : "+v"(a2), "+v"(b2));
    acc0 += a2.x * __logf(b2.x + EPS);
    acc1 += a2.y * __logf(b2.y + EPS);
    acc2 += a2.z * __logf(b2.z + EPS);
    acc3 += a2.w * __logf(b2.w + EPS);

    asm volatile("s_waitcnt vmcnt(0)" : "+v"(a3), "+v"(b3));
    acc0 += a3.x * __logf(b3.x + EPS);
    acc1 += a3.y * __logf(b3.y + EPS);
    acc2 += a3.z * __logf(b3.z + EPS);
    acc3 += a3.w * __logf(b3.w + EPS);

    float acc = (acc0 + acc1) + (acc2 + acc3);

    // wave-64 shuffle reduction
    #pragma unroll
    for (int off = 32; off > 0; off >>= 1)
        acc += __shfl_down(acc, off, 64);

    __shared__ float wave_sums[BLOCK / 64];
    int lane = threadIdx.x & 63;
    int wid  = threadIdx.x >> 6;
    if (lane == 0) wave_sums[wid] = acc;
    __syncthreads();

    if (threadIdx.x == 0) {
        float s = wave_sums[0] + wave_sums[1] + wave_sums[2] + wave_sums[3];
        partials[blockIdx.x] = s;  // deterministic, no atomics
    }
}

__global__ __launch_bounds__(BLOCK) void cep_final_kernel(
        const float* __restrict__ partials, float* __restrict__ out, int nparts) {
    float acc = 0.0f;
    for (int i = threadIdx.x; i < nparts; i += BLOCK)
        acc += partials[i];

    #pragma unroll
    for (int off = 32; off > 0; off >>= 1)
        acc += __shfl_down(acc, off, 64);

    __shared__ float wave_sums[BLOCK / 64];
    int lane = threadIdx.x & 63;
    int wid  = threadIdx.x >> 6;
    if (lane == 0) wave_sums[wid] = acc;
    __syncthreads();

    if (threadIdx.x == 0) {
        float s = wave_sums[0] + wave_sums[1] + wave_sums[2] + wave_sums[3];
        out[0] = -s;
    }
}

extern "C" void kernel_launch(void* const* d_in, const int* in_sizes, int n_in,
                              void* d_out, int out_size, void* d_ws, size_t ws_size,
                              hipStream_t stream) {
    const float* d1 = (const float*)d_in[0];
    const float* d2 = (const float*)d_in[1];
    float* out = (float*)d_out;
    float* partials = (float*)d_ws;

    int n = in_sizes[0];  // 16,777,216 = 4096^2
    // Each thread consumes 16 floats per input -> grid = n / (BLOCK*16) = 4096
    const int grid = n / (BLOCK * 16);

    cep_loss_kernel<<<grid, BLOCK, 0, stream>>>(d1, d2, partials);
    cep_final_kernel<<<1, BLOCK, 0, stream>>>(partials, out, grid);
}

// Round 7
// 146.627 us; speedup vs baseline: 1.0131x; 1.0131x over previous
//
#include <hip/hip_runtime.h>
#include <math.h>

// loss = -sum_ij d1[i,j] * log(d2[i,j] + 1e-5), fp32 in, scalar fp32 out.
// R1-R5: three structures plateau at 134MB/42.6us = 3.15 TB/s (5.1 B/cyc/CU
// read); fill kernel shows 6.4 TB/s write-only. R6 hypothesis (untested due
// to crash): 100% residency (exactly 8 blocks/CU) + CONTINUOUSLY sustained
// 8 loads outstanding per wave via rolling pipeline, vs one-shot burst that
// drains to zero during compute/reduce/exit.
// R6 crash root-cause: asm outputs without early-clobber could be allocated
// over the 64-bit address-pair inputs of the SAME block -> first load
// clobbers second load's address -> fault. Fix: "=&v" on every output.

#define EPS 1e-5f
#define BLOCK 256

typedef float v4f __attribute__((ext_vector_type(4)));

#define COMPUTE_PAIR(A_, B_)                 \
    acc0 += (A_).x * __logf((B_).x + EPS);   \
    acc1 += (A_).y * __logf((B_).y + EPS);   \
    acc2 += (A_).z * __logf((B_).z + EPS);   \
    acc3 += (A_).w * __logf((B_).w + EPS);

__global__ __launch_bounds__(BLOCK) void cep_loss_kernel(
        const float* __restrict__ d1,
        const float* __restrict__ d2,
        float* __restrict__ partials) {
    // Each block consumes 8 chunks x 4KB per input (32KB/input/block).
    // Chunk k byte addr: blockIdx*32768 + k*4096 + tid*16 (lane-contiguous).
    // Base pointers parked at odd chunks; even chunks via offset:-4096
    // (13-bit signed imm: -4096 encodes, +4096 does not).
    size_t tb = (size_t)blockIdx.x * 32768 + (size_t)threadIdx.x * 16;
    const char* a1 = (const char*)d1 + tb + 4096;    // chunks 0,1
    const char* a3 = (const char*)d1 + tb + 12288;   // chunks 2,3
    const char* a5 = (const char*)d1 + tb + 20480;   // chunks 4,5
    const char* a7 = (const char*)d1 + tb + 28672;   // chunks 6,7
    const char* b1 = (const char*)d2 + tb + 4096;
    const char* b3 = (const char*)d2 + tb + 12288;
    const char* b5 = (const char*)d2 + tb + 20480;
    const char* b7 = (const char*)d2 + tb + 28672;

    v4f A0, A1, A2, A3, B0, B1, B2, B3;
    float acc0 = 0.f, acc1 = 0.f, acc2 = 0.f, acc3 = 0.f;

    // Prologue: issue pairs 0-3 (8 loads, 8KB/wave outstanding).
    // "=&v": outputs must not alias the address pairs read by later
    // instructions in this block.
    asm volatile(
        "global_load_dwordx4 %0, %8, off offset:-4096\n\t"
        "global_load_dwordx4 %4, %10, off offset:-4096\n\t"
        "global_load_dwordx4 %1, %8, off\n\t"
        "global_load_dwordx4 %5, %10, off\n\t"
        "global_load_dwordx4 %2, %9, off offset:-4096\n\t"
        "global_load_dwordx4 %6, %11, off offset:-4096\n\t"
        "global_load_dwordx4 %3, %9, off\n\t"
        "global_load_dwordx4 %7, %11, off\n\t"
        : "=&v"(A0), "=&v"(A1), "=&v"(A2), "=&v"(A3),
          "=&v"(B0), "=&v"(B1), "=&v"(B2), "=&v"(B3)
        : "v"(a1), "v"(a3), "v"(b1), "v"(b3)
        : "memory");

    // Steady state: wait oldest pair (vmcnt(6)), compute it, reissue into
    // the freed buffer. Outstanding stays at 8 until the epilogue.
    asm volatile("s_waitcnt vmcnt(6)" : "+v"(A0), "+v"(B0));
    COMPUTE_PAIR(A0, B0)
    asm volatile(
        "global_load_dwordx4 %0, %2, off offset:-4096\n\t"
        "global_load_dwordx4 %1, %3, off offset:-4096\n\t"
        : "=&v"(A0), "=&v"(B0) : "v"(a5), "v"(b5) : "memory");

    asm volatile("s_waitcnt vmcnt(6)" : "+v"(A1), "+v"(B1));
    COMPUTE_PAIR(A1, B1)
    asm volatile(
        "global_load_dwordx4 %0, %2, off\n\t"
        "global_load_dwordx4 %1, %3, off\n\t"
        : "=&v"(A1), "=&v"(B1) : "v"(a5), "v"(b5) : "memory");

    asm volatile("s_waitcnt vmcnt(6)" : "+v"(A2), "+v"(B2));
    COMPUTE_PAIR(A2, B2)
    asm volatile(
        "global_load_dwordx4 %0, %2, off offset:-4096\n\t"
        "global_load_dwordx4 %1, %3, off offset:-4096\n\t"
        : "=&v"(A2), "=&v"(B2) : "v"(a7), "v"(b7) : "memory");

    asm volatile("s_waitcnt vmcnt(6)" : "+v"(A3), "+v"(B3));
    COMPUTE_PAIR(A3, B3)
    asm volatile(
        "global_load_dwordx4 %0, %2, off\n\t"
        "global_load_dwordx4 %1, %3, off\n\t"
        : "=&v"(A3), "=&v"(B3) : "v"(a7), "v"(b7) : "memory");

    // Epilogue: drain pairs 4-7.
    asm volatile("s_waitcnt vmcnt(6)" : "+v"(A0), "+v"(B0));
    COMPUTE_PAIR(A0, B0)
    asm volatile("s_waitcnt vmcnt(4)" : "+v"(A1), "+v"(B1));
    COMPUTE_PAIR(A1, B1)
    asm volatile("s_waitcnt vmcnt(2)" : "+v"(A2), "+v"(B2));
    COMPUTE_PAIR(A2, B2)
    asm volatile("s_waitcnt vmcnt(0)" : "+v"(A3), "+v"(B3));
    COMPUTE_PAIR(A3, B3)

    float acc = (acc0 + acc1) + (acc2 + acc3);

    // wave-64 shuffle reduction
    #pragma unroll
    for (int off = 32; off > 0; off >>= 1)
        acc += __shfl_down(acc, off, 64);

    __shared__ float wave_sums[BLOCK / 64];
    int lane = threadIdx.x & 63;
    int wid  = threadIdx.x >> 6;
    if (lane == 0) wave_sums[wid] = acc;
    __syncthreads();

    if (threadIdx.x == 0) {
        float s = wave_sums[0] + wave_sums[1] + wave_sums[2] + wave_sums[3];
        partials[blockIdx.x] = s;  // deterministic, no atomics
    }
}

__global__ __launch_bounds__(BLOCK) void cep_final_kernel(
        const float* __restrict__ partials, float* __restrict__ out, int nparts) {
    float acc = 0.0f;
    for (int i = threadIdx.x; i < nparts; i += BLOCK)
        acc += partials[i];

    #pragma unroll
    for (int off = 32; off > 0; off >>= 1)
        acc += __shfl_down(acc, off, 64);

    __shared__ float wave_sums[BLOCK / 64];
    int lane = threadIdx.x & 63;
    int wid  = threadIdx.x >> 6;
    if (lane == 0) wave_sums[wid] = acc;
    __syncthreads();

    if (threadIdx.x == 0) {
        float s = wave_sums[0] + wave_sums[1] + wave_sums[2] + wave_sums[3];
        out[0] = -s;
    }
}

extern "C" void kernel_launch(void* const* d_in, const int* in_sizes, int n_in,
                              void* d_out, int out_size, void* d_ws, size_t ws_size,
                              hipStream_t stream) {
    const float* d1 = (const float*)d_in[0];
    const float* d2 = (const float*)d_in[1];
    float* out = (float*)d_out;
    float* partials = (float*)d_ws;

    // N = 4096^2. Each block consumes 8192 floats per input (32KB).
    // grid = 16,777,216 / 8192 = 2048 = exactly 8 blocks/CU, all resident.
    const int grid = in_sizes[0] / (BLOCK * 32);

    cep_loss_kernel<<<grid, BLOCK, 0, stream>>>(d1, d2, partials);
    cep_final_kernel<<<1, BLOCK, 0, stream>>>(partials, out, grid);
}

// Round 8
// 144.862 us; speedup vs baseline: 1.0254x; 1.0122x over previous
//
#include <hip/hip_runtime.h>
#include <math.h>

// loss = -sum_ij d1[i,j] * log(d2[i,j] + 1e-5), fp32 in, scalar fp32 out.
// R1-R7: four distinct VGPR-return-load structures all plateau at
// 134MB/~44us = 3.0-3.2 TB/s = ~5 B/cyc/CU, with HBM at 18% and VALU at 13%.
// Model: per-CU outstanding-read cap on the VGPR-return path (rate=cap/lat).
// This round: the OTHER read path - global_load_lds DMA (no VGPR return,
// possibly separate/deeper queue; the hipBLASLt staging path). Per-wave
// self-contained pipeline, no barriers: 4-slot LDS ring per wave, prefetch
// depth 3 (6 outstanding DMA = 6KB/wave sustained), explicit vmcnt waits.

#define EPS 1e-5f
#define BLOCK 256
#define STAGES 8

typedef float v4f __attribute__((ext_vector_type(4)));

#define COMPUTE_PAIR(A_, B_)                 \
    acc0 += (A_).x * __logf((B_).x + EPS);   \
    acc1 += (A_).y * __logf((B_).y + EPS);   \
    acc2 += (A_).z * __logf((B_).z + EPS);   \
    acc3 += (A_).w * __logf((B_).w + EPS);

__global__ __launch_bounds__(BLOCK) void cep_loss_kernel(
        const float* __restrict__ d1,
        const float* __restrict__ d2,
        float* __restrict__ partials) {
    // Per block per input: 8 stages x 1024 floats (4KB) = 8192 floats (32KB).
    // Stage layout: wave w stages floats [s*1024 + w*256, +256) via ONE
    // global_load_lds_dwordx4 (64 lanes x 16B = 1KB, lane-contiguous,
    // LDS dest = wave-uniform base + lane*16 -- matches the HW rule).
    __shared__ float lds_a[4][1024];   // 4-slot ring, slot = stage & 3
    __shared__ float lds_b[4][1024];

    int lane = threadIdx.x & 63;
    int wave = threadIdx.x >> 6;
    size_t blockBase = (size_t)blockIdx.x * (STAGES * 1024);  // floats
    size_t waveBase  = blockBase + wave * 256 + lane * 4;     // + s*1024

    const float* g1 = d1 + waveBase;
    const float* g2 = d2 + waveBase;
    int ldsWave = wave * 256;  // float index of this wave's slice in a slot

    #define ISSUE_STAGE(s_)                                                        \
        __builtin_amdgcn_global_load_lds(                                          \
            (const __attribute__((address_space(1))) unsigned int*)(g1 + (s_) * 1024), \
            (__attribute__((address_space(3))) unsigned int*)&lds_a[(s_) & 3][ldsWave], \
            16, 0, 0);                                                             \
        __builtin_amdgcn_global_load_lds(                                          \
            (const __attribute__((address_space(1))) unsigned int*)(g2 + (s_) * 1024), \
            (__attribute__((address_space(3))) unsigned int*)&lds_b[(s_) & 3][ldsWave], \
            16, 0, 0);

    float acc0 = 0.f, acc1 = 0.f, acc2 = 0.f, acc3 = 0.f;

    // Prologue: fill 3 of the 4 ring slots (6 DMA outstanding).
    ISSUE_STAGE(0)
    ISSUE_STAGE(1)
    ISSUE_STAGE(2)

    #pragma unroll
    for (int s = 0; s < STAGES; s++) {
        if (s + 3 < STAGES) { ISSUE_STAGE(s + 3) }
        // Wait until stage s's pair has landed: newer outstanding =
        // 2*(issued_through - s), issued_through = min(s+3, STAGES-1).
        int newer = 2 * ((s + 3 < STAGES ? s + 3 : STAGES - 1) - s);
        switch (newer) {
            case 6: asm volatile("s_waitcnt vmcnt(6)" ::: "memory"); break;
            case 4: asm volatile("s_waitcnt vmcnt(4)" ::: "memory"); break;
            case 2: asm volatile("s_waitcnt vmcnt(2)" ::: "memory"); break;
            default: asm volatile("s_waitcnt vmcnt(0)" ::: "memory"); break;
        }
        v4f A = *(const v4f*)&lds_a[s & 3][ldsWave + lane * 4];
        v4f B = *(const v4f*)&lds_b[s & 3][ldsWave + lane * 4];
        COMPUTE_PAIR(A, B)
    }

    float acc = (acc0 + acc1) + (acc2 + acc3);

    // wave-64 shuffle reduction
    #pragma unroll
    for (int off = 32; off > 0; off >>= 1)
        acc += __shfl_down(acc, off, 64);

    __shared__ float wave_sums[BLOCK / 64];
    if (lane == 0) wave_sums[wave] = acc;
    __syncthreads();

    if (threadIdx.x == 0) {
        float s = wave_sums[0] + wave_sums[1] + wave_sums[2] + wave_sums[3];
        partials[blockIdx.x] = s;  // deterministic, no atomics
    }
}

__global__ __launch_bounds__(BLOCK) void cep_final_kernel(
        const float* __restrict__ partials, float* __restrict__ out, int nparts) {
    float acc = 0.0f;
    for (int i = threadIdx.x; i < nparts; i += BLOCK)
        acc += partials[i];

    #pragma unroll
    for (int off = 32; off > 0; off >>= 1)
        acc += __shfl_down(acc, off, 64);

    __shared__ float wave_sums[BLOCK / 64];
    int lane = threadIdx.x & 63;
    int wid  = threadIdx.x >> 6;
    if (lane == 0) wave_sums[wid] = acc;
    __syncthreads();

    if (threadIdx.x == 0) {
        float s = wave_sums[0] + wave_sums[1] + wave_sums[2] + wave_sums[3];
        out[0] = -s;
    }
}

extern "C" void kernel_launch(void* const* d_in, const int* in_sizes, int n_in,
                              void* d_out, int out_size, void* d_ws, size_t ws_size,
                              hipStream_t stream) {
    const float* d1 = (const float*)d_in[0];
    const float* d2 = (const float*)d_in[1];
    float* out = (float*)d_out;
    float* partials = (float*)d_ws;

    // N = 4096^2 floats. Each block consumes 8192 floats/input (32KB).
    const int grid = in_sizes[0] / (STAGES * 1024);  // 2048

    cep_loss_kernel<<<grid, BLOCK, 0, stream>>>(d1, d2, partials);
    cep_final_kernel<<<1, BLOCK, 0, stream>>>(partials, out, grid);
}